// Round 3
// baseline (770.761 us; speedup 1.0000x reference)
//
#include <hip/hip_runtime.h>

// ROI pooling 3D: segment-mean of feat (2,64,96,112,96) fp32 over atlas (91,109,91), segs 1..94.
constexpr int SEG_N   = 95;
constexpr int CROP_D  = 91, CROP_H = 109, CROP_W = 91;
constexpr int NVOX    = CROP_D * CROP_H * CROP_W;     // 902629
constexpr int LINES   = CROP_D * CROP_H;              // 9919
constexpr int FEAT_W  = 96;
constexpr int FEAT_HW = 112 * 96;                     // 10752
constexpr int CSTRIDE = 96 * 112 * 96;                // per-(b,c) plane elements
constexpr int PVOX    = LINES * FEAT_W;               // 952224 padded voxels (w 91..95 -> trash)
constexpr int UNITS   = PVOX / 32;                    // 29757 exact
constexpr int BIN_ROWS= 96;                           // 95 segs + trash row
constexpr int NBC     = 128;
constexpr int BIN_SZ  = BIN_ROWS * NBC;               // 12288 floats per partial
constexpr int GRID    = 512;                          // 2 blocks/CU
constexpr int OUT_N   = 2 * 94 * 64;
constexpr size_t PART_OFF = 4096;                     // cnts live at ws+0
constexpr size_t WS_NEED  = PART_OFF + (size_t)GRID * BIN_SZ * sizeof(float);

// Core: per ds_add instruction, ONE voxel (uniform seg) x 64 distinct channels ->
// all LDS atomic addresses distinct -> no same-address serialization.
__global__ __launch_bounds__(256) void seg_accum(const float* __restrict__ feat,
                                                 const int*   __restrict__ atlas,
                                                 float* __restrict__ part,
                                                 int use_atomic)
{
    __shared__ float bins[BIN_ROWS][NBC];             // 49.2 KB
    const int tid = threadIdx.x;
    for (int i = tid; i < BIN_SZ; i += 256) ((float*)bins)[i] = 0.0f;
    __syncthreads();

    const int wv   = tid >> 6, lane = tid & 63;
    const int pair = wv >> 1;                         // which 16-voxel half of the unit
    const int cg   = wv & 1;                          // channel group: 0..63 / 64..127
    const float* __restrict__ fb = feat + (size_t)(cg * 64 + lane) * CSTRIDE;
    float* __restrict__ bcol = &bins[0][cg * 64 + lane];

    for (int unit = blockIdx.x; unit < UNITS; unit += gridDim.x) {
        const int v0 = unit * 32 + pair * 16;         // padded voxel base (mult of 16)

        // lanes 0..15: atlas id for voxel v0+lane (95 = pad/trash)
        int myid = 95;
        if (lane < 16) {
            const int vme  = v0 + lane;
            const int line = vme / FEAT_W;
            const int ww   = vme - line * FEAT_W;
            if (ww < CROP_W) myid = atlas[line * CROP_W + ww];
        }

        // 4 quads of 4 voxels; quads never cross lines (96 % 4 == 0)
        float4 vals[4];
        #pragma unroll
        for (int j = 0; j < 4; ++j) {
            const int vq   = v0 + j * 4;
            const int line = vq / FEAT_W;
            const int ww   = vq - line * FEAT_W;
            const int lb   = (line / CROP_H) * FEAT_HW + (line - (line / CROP_H) * CROP_H) * FEAT_W;
            vals[j] = *(const float4*)(fb + lb + ww); // lane stride = CSTRIDE (4 MB)
        }

        #pragma unroll
        for (int j = 0; j < 4; ++j) {
            const float* vv = (const float*)&vals[j];
            #pragma unroll
            for (int e = 0; e < 4; ++e) {
                const int id = __builtin_amdgcn_readlane(myid, j * 4 + e); // wave-uniform seg
                atomicAdd(bcol + id * NBC, vv[e]);    // 64 distinct addresses, 2-way banks
            }
        }
    }
    __syncthreads();

    if (!use_atomic) {
        float* p = part + (size_t)blockIdx.x * BIN_SZ;
        for (int i = tid; i < BIN_SZ; i += 256) p[i] = ((float*)bins)[i];
    } else {
        for (int i = tid; i < BIN_SZ; i += 256) unsafeAtomicAdd(&part[i], ((float*)bins)[i]);
    }
}

__global__ __launch_bounds__(256) void seg_count(const int* __restrict__ atlas,
                                                 int* __restrict__ cnts)
{
    __shared__ int cbin[SEG_N];
    const int tid = threadIdx.x;
    for (int i = tid; i < SEG_N; i += 256) cbin[i] = 0;
    __syncthreads();
    for (int i = blockIdx.x * 256 + tid; i < NVOX; i += gridDim.x * 256)
        atomicAdd(&cbin[atlas[i]], 1);
    __syncthreads();
    for (int i = tid; i < SEG_N; i += 256) atomicAdd(&cnts[i], cbin[i]);
}

__global__ __launch_bounds__(256) void reduce_fin(const float* __restrict__ part,
                                                  const int*   __restrict__ cnts,
                                                  float* __restrict__ out,
                                                  int nparts)
{
    const int idx = blockIdx.x * 256 + threadIdx.x;
    if (idx >= OUT_N) return;
    const int c   = idx & 63;
    const int s0  = (idx >> 6) % 94;
    const int b   = idx / (94 * 64);
    const int seg = s0 + 1;
    const int ch  = b * 64 + c;
    float s = 0.0f;
    for (int k = 0; k < nparts; ++k)
        s += part[(size_t)k * BIN_SZ + seg * NBC + ch];   // coalesced across idx
    const float den = fmaxf((float)cnts[seg], 1e-6f);
    out[idx] = s / den;
}

extern "C" void kernel_launch(void* const* d_in, const int* in_sizes, int n_in,
                              void* d_out, int out_size, void* d_ws, size_t ws_size,
                              hipStream_t stream)
{
    const float* feat  = (const float*)d_in[0];
    const int*   atlas = (const int*)d_in[1];
    float* out  = (float*)d_out;
    int*   cnts = (int*)d_ws;
    float* part = (float*)((char*)d_ws + PART_OFF);
    const int use_atomic = (ws_size < WS_NEED) ? 1 : 0;
    const int nparts = use_atomic ? 1 : GRID;

    // zero cnts (+ part[0] for the atomic fallback); partials are fully overwritten otherwise
    hipMemsetAsync(d_ws, 0, PART_OFF + (size_t)BIN_SZ * sizeof(float), stream);

    seg_count<<<256, 256, 0, stream>>>(atlas, cnts);
    seg_accum<<<GRID, 256, 0, stream>>>(feat, atlas, part, use_atomic);
    reduce_fin<<<(OUT_N + 255) / 256, 256, 0, stream>>>(part, cnts, out, nparts);
}

// Round 5
// 348.480 us; speedup vs baseline: 2.2118x; 2.2118x over previous
//
#include <hip/hip_runtime.h>

// ROI pooling 3D as one-hot MFMA GEMM (transposed): part[ch][seg] = sum_v feat[ch][v] * onehot[v][seg].
// No LDS, no atomics in the hot loop.
constexpr int SEG_N   = 95;
constexpr int CROP_D  = 91, CROP_H = 109, CROP_W = 91;
constexpr int NVOX    = CROP_D * CROP_H * CROP_W;     // 902629
constexpr int LINES   = CROP_D * CROP_H;              // 9919
constexpr int FEAT_W  = 96;
constexpr int FEAT_HW = 112 * 96;
constexpr int CSTRIDE = 96 * 112 * 96;                // per-(b,c) elements
constexpr int NTILE   = LINES * 3;                    // 29757 tiles of 32 voxels (3 per line, exact)
constexpr int NBC     = 128;
constexpr int PSEG    = 96;                           // 95 segs + trash row 95
constexpr int BIN_SZ  = NBC * PSEG;                   // 12288 floats per block partial, [ch][seg]
constexpr int GRID    = 512;
constexpr int OUT_N   = 2 * 94 * 64;
constexpr size_t PART_OFF = 4096;
constexpr size_t WS_NEED  = PART_OFF + (size_t)GRID * BIN_SZ * sizeof(float);

typedef __attribute__((ext_vector_type(8))) short bf16x8;
typedef __attribute__((ext_vector_type(4))) float f32x4;

__device__ inline unsigned int rne2(float a, float b) {   // 2x fp32 -> packed bf16 (RNE)
    unsigned int x = __float_as_uint(a), y = __float_as_uint(b);
    x = (x + 0x7FFFu + ((x >> 16) & 1u)) >> 16;
    y = (y + 0x7FFFu + ((y >> 16) & 1u)) & 0xFFFF0000u;
    return x | y;
}

__global__ __launch_bounds__(256) void seg_mfma(const float* __restrict__ feat,
                                                const int*   __restrict__ atlas,
                                                float* __restrict__ part,
                                                int use_atomic)
{
    const int tid = threadIdx.x, wv = tid >> 6, lane = tid & 63;
    const int l15 = lane & 15, lq = lane >> 4;

    f32x4 acc[2][6];                                   // [ch-subtile][seg-tile] = 48 VGPRs
    #pragma unroll
    for (int a = 0; a < 2; ++a)
        #pragma unroll
        for (int s = 0; s < 6; ++s) acc[a][s] = (f32x4){0.f, 0.f, 0.f, 0.f};

    for (int t = blockIdx.x; t < NTILE; t += GRID) {
        const int line  = t / 3;                       // tile = 32 voxels inside one 96-wide line
        const int w0    = (t - line * 3) * 32;
        const int d     = line / CROP_H, h = line - d * CROP_H;
        const int lbase = d * FEAT_HW + h * FEAT_W + w0;
        const int abase = line * CROP_W + w0;

        // atlas ids for this lane's k-quarter: k = lq*8 + j  (w >= 91 -> trash seg 95)
        int id[8];
        const int wq = w0 + lq * 8;
        #pragma unroll
        for (int j = 0; j < 8; ++j)
            id[j] = (wq + j < CROP_W) ? atlas[abase + lq * 8 + j] : 95;

        // B one-hot fragments per seg-tile: col = l15 (seg), k = lq*8 + j. Values in {0, 1.0bf16}.
        unsigned int bu[6][4];
        #pragma unroll
        for (int sb = 0; sb < 6; ++sb) {
            const int seg = sb * 16 + l15;
            #pragma unroll
            for (int p = 0; p < 4; ++p) {
                const unsigned int lo = (id[2 * p]     == seg) ? 0x3F80u     : 0u;
                const unsigned int hi = (id[2 * p + 1] == seg) ? 0x3F800000u : 0u;
                bu[sb][p] = lo | hi;
            }
        }

        // A fragments: row = l15 -> ch, k = lq*8 + j. One full 128B line per (ch, tile).
        #pragma unroll
        for (int a = 0; a < 2; ++a) {
            const int ch = wv * 32 + a * 16 + l15;
            const float* fp = feat + (size_t)ch * CSTRIDE + lbase + lq * 8;
            const float4 v0 = *(const float4*)fp;
            const float4 v1 = *(const float4*)(fp + 4);
            union { bf16x8 v; unsigned int u[4]; } A;
            A.u[0] = rne2(v0.x, v0.y); A.u[1] = rne2(v0.z, v0.w);
            A.u[2] = rne2(v1.x, v1.y); A.u[3] = rne2(v1.z, v1.w);
            #pragma unroll
            for (int sb = 0; sb < 6; ++sb) {
                union { bf16x8 v; unsigned int u[4]; } B;
                B.u[0] = bu[sb][0]; B.u[1] = bu[sb][1];
                B.u[2] = bu[sb][2]; B.u[3] = bu[sb][3];
                acc[a][sb] = __builtin_amdgcn_mfma_f32_16x16x32_bf16(A.v, B.v, acc[a][sb], 0, 0, 0);
            }
        }
    }

    // Epilogue: D row = lq*4 + r (ch within 16), col = l15 (seg). Waves own disjoint ch rows.
    float* p = part + (use_atomic ? 0 : (size_t)blockIdx.x * BIN_SZ);
    #pragma unroll
    for (int a = 0; a < 2; ++a)
        #pragma unroll
        for (int sb = 0; sb < 6; ++sb)
            #pragma unroll
            for (int r = 0; r < 4; ++r) {
                const int ch  = wv * 32 + a * 16 + lq * 4 + r;
                const int seg = sb * 16 + l15;
                if (use_atomic) unsafeAtomicAdd(&p[ch * PSEG + seg], acc[a][sb][r]);
                else            p[ch * PSEG + seg] = acc[a][sb][r];
            }
}

__global__ __launch_bounds__(256) void seg_count(const int* __restrict__ atlas,
                                                 int* __restrict__ cnts)
{
    __shared__ int cbin[SEG_N];
    const int tid = threadIdx.x;
    for (int i = tid; i < SEG_N; i += 256) cbin[i] = 0;
    __syncthreads();
    for (int i = blockIdx.x * 256 + tid; i < NVOX; i += gridDim.x * 256)
        atomicAdd(&cbin[atlas[i]], 1);
    __syncthreads();
    for (int i = tid; i < SEG_N; i += 256) atomicAdd(&cnts[i], cbin[i]);
}

__global__ __launch_bounds__(256) void reduce_fin(const float* __restrict__ part,
                                                  const int*   __restrict__ cnts,
                                                  float* __restrict__ out,
                                                  int nparts)
{
    const int idx = blockIdx.x * 256 + threadIdx.x;
    if (idx >= OUT_N) return;
    const int c   = idx & 63;
    const int s0  = (idx >> 6) % 94;
    const int b   = idx / (94 * 64);
    const int seg = s0 + 1;
    const int ch  = b * 64 + c;
    float s = 0.0f;
    for (int k = 0; k < nparts; ++k)
        s += part[(size_t)k * BIN_SZ + ch * PSEG + seg];
    const float den = fmaxf((float)cnts[seg], 1e-6f);
    out[idx] = s / den;
}

extern "C" void kernel_launch(void* const* d_in, const int* in_sizes, int n_in,
                              void* d_out, int out_size, void* d_ws, size_t ws_size,
                              hipStream_t stream)
{
    const float* feat  = (const float*)d_in[0];
    const int*   atlas = (const int*)d_in[1];
    float* out  = (float*)d_out;
    int*   cnts = (int*)d_ws;
    float* part = (float*)((char*)d_ws + PART_OFF);
    const int use_atomic = (ws_size < WS_NEED) ? 1 : 0;
    const int nparts = use_atomic ? 1 : GRID;

    // zero cnts (+ partial[0] for the atomic fallback)
    hipMemsetAsync(d_ws, 0, PART_OFF + (size_t)BIN_SZ * sizeof(float), stream);

    seg_count<<<256, 256, 0, stream>>>(atlas, cnts);
    seg_mfma<<<GRID, 256, 0, stream>>>(feat, atlas, part, use_atomic);
    reduce_fin<<<(OUT_N + 255) / 256, 256, 0, stream>>>(part, cnts, out, nparts);
}

// Round 6
// 147.689 us; speedup vs baseline: 5.2188x; 2.3595x over previous
//
#include <hip/hip_runtime.h>

// ROI pooling 3D as one-hot MFMA GEMM (transposed): part[ch][seg] = sum_v feat[ch][v] * onehot[v][seg].
// No LDS, no atomics in the hot loop; deterministic FP reduction tree.
constexpr int SEG_N   = 95;
constexpr int CROP_D  = 91, CROP_H = 109, CROP_W = 91;
constexpr int NVOX    = CROP_D * CROP_H * CROP_W;     // 902629
constexpr int LINES   = CROP_D * CROP_H;              // 9919
constexpr int FEAT_W  = 96;
constexpr int FEAT_HW = 112 * 96;
constexpr int CSTRIDE = 96 * 112 * 96;                // per-(b,c) elements
constexpr int NTILE   = LINES * 3;                    // 29757 tiles of 32 voxels (exact)
constexpr int NBC     = 128;
constexpr int PSEG    = 96;                           // 95 segs + trash col 95
constexpr int BIN_SZ  = NBC * PSEG;                   // 12288 floats per partial, [ch][seg]
constexpr int GRID    = 1024;                         // 4 blocks/CU
constexpr int NCHUNK  = 16;                           // stage-A outputs
constexpr int KPC     = GRID / NCHUNK;                // 64 partials per chunk
constexpr int OUT_N   = 2 * 94 * 64;
constexpr size_t PART_OFF  = 4096;
constexpr size_t PART2_OFF = PART_OFF + (size_t)GRID * BIN_SZ * sizeof(float);
constexpr size_t WS_NEED   = PART2_OFF + (size_t)NCHUNK * BIN_SZ * sizeof(float);

typedef __attribute__((ext_vector_type(8))) short bf16x8;
typedef __attribute__((ext_vector_type(4))) float f32x4;

__device__ inline unsigned int rne2(float a, float b) {   // 2x fp32 -> packed bf16 (RNE)
    unsigned int x = __float_as_uint(a), y = __float_as_uint(b);
    x = (x + 0x7FFFu + ((x >> 16) & 1u)) >> 16;
    y = (y + 0x7FFFu + ((y >> 16) & 1u)) & 0xFFFF0000u;
    return x | y;
}

// Replaces hipMemsetAsync (52 KB fill showed 316 us inside the captured graph).
__global__ __launch_bounds__(256) void zero_ws(unsigned int* __restrict__ w)
{
    const int i = blockIdx.x * 256 + threadIdx.x;     // covers cnts region + part[0]
    if (i < (int)(PART_OFF / 4) + BIN_SZ) w[i] = 0u;
}

__global__ __launch_bounds__(256) void seg_mfma(const float* __restrict__ feat,
                                                const int*   __restrict__ atlas,
                                                float* __restrict__ part,
                                                int use_atomic)
{
    const int tid = threadIdx.x, wv = tid >> 6, lane = tid & 63;
    const int l15 = lane & 15, lq = lane >> 4;

    f32x4 acc[2][6];                                   // [ch-subtile][seg-tile] = 48 VGPRs
    #pragma unroll
    for (int a = 0; a < 2; ++a)
        #pragma unroll
        for (int s = 0; s < 6; ++s) acc[a][s] = (f32x4){0.f, 0.f, 0.f, 0.f};

    for (int t = blockIdx.x; t < NTILE; t += GRID) {
        const int line  = t / 3;                       // tile = 32 voxels inside one 96-wide line
        const int w0    = (t - line * 3) * 32;
        const int d     = line / CROP_H, h = line - d * CROP_H;
        const int lbase = d * FEAT_HW + h * FEAT_W + w0;
        const int abase = line * CROP_W + w0;

        // atlas ids for this lane's k-quarter: k = lq*8 + j  (w >= 91 -> trash seg 95)
        int id[8];
        const int wq = w0 + lq * 8;
        #pragma unroll
        for (int j = 0; j < 8; ++j)
            id[j] = (wq + j < CROP_W) ? atlas[abase + lq * 8 + j] : 95;

        // B one-hot fragments per seg-tile: col = l15 (seg), k = lq*8 + j. Values in {0, 1.0bf16}.
        unsigned int bu[6][4];
        #pragma unroll
        for (int sb = 0; sb < 6; ++sb) {
            const int seg = sb * 16 + l15;
            #pragma unroll
            for (int p = 0; p < 4; ++p) {
                const unsigned int lo = (id[2 * p]     == seg) ? 0x3F80u     : 0u;
                const unsigned int hi = (id[2 * p + 1] == seg) ? 0x3F800000u : 0u;
                bu[sb][p] = lo | hi;
            }
        }

        // A fragments: row = l15 -> ch, k = lq*8 + j. One full 128B line per (ch, tile).
        #pragma unroll
        for (int a = 0; a < 2; ++a) {
            const int ch = wv * 32 + a * 16 + l15;
            const float* fp = feat + (size_t)ch * CSTRIDE + lbase + lq * 8;
            const float4 v0 = *(const float4*)fp;
            const float4 v1 = *(const float4*)(fp + 4);
            union { bf16x8 v; unsigned int u[4]; } A;
            A.u[0] = rne2(v0.x, v0.y); A.u[1] = rne2(v0.z, v0.w);
            A.u[2] = rne2(v1.x, v1.y); A.u[3] = rne2(v1.z, v1.w);
            #pragma unroll
            for (int sb = 0; sb < 6; ++sb) {
                union { bf16x8 v; unsigned int u[4]; } B;
                B.u[0] = bu[sb][0]; B.u[1] = bu[sb][1];
                B.u[2] = bu[sb][2]; B.u[3] = bu[sb][3];
                acc[a][sb] = __builtin_amdgcn_mfma_f32_16x16x32_bf16(A.v, B.v, acc[a][sb], 0, 0, 0);
            }
        }
    }

    // Epilogue: D row = lq*4 + r (ch within 16), col = l15 (seg). Waves own disjoint ch rows.
    float* p = part + (use_atomic ? 0 : (size_t)blockIdx.x * BIN_SZ);
    #pragma unroll
    for (int a = 0; a < 2; ++a)
        #pragma unroll
        for (int sb = 0; sb < 6; ++sb)
            #pragma unroll
            for (int r = 0; r < 4; ++r) {
                const int ch  = wv * 32 + a * 16 + lq * 4 + r;
                const int seg = sb * 16 + l15;
                if (use_atomic) unsafeAtomicAdd(&p[ch * PSEG + seg], acc[a][sb][r]);
                else            p[ch * PSEG + seg] = acc[a][sb][r];
            }
}

__global__ __launch_bounds__(256) void seg_count(const int* __restrict__ atlas,
                                                 int* __restrict__ cnts)
{
    __shared__ int cbin[SEG_N];
    const int tid = threadIdx.x;
    for (int i = tid; i < SEG_N; i += 256) cbin[i] = 0;
    __syncthreads();
    for (int i = blockIdx.x * 256 + tid; i < NVOX; i += gridDim.x * 256)
        atomicAdd(&cbin[atlas[i]], 1);
    __syncthreads();
    for (int i = tid; i < SEG_N; i += 256) atomicAdd(&cnts[i], cbin[i]);
}

// Stage A: sum GRID partials down to NCHUNK, coalesced across elem.
__global__ __launch_bounds__(256) void reduce_stageA(const float* __restrict__ part,
                                                     float* __restrict__ part2,
                                                     int active)
{
    if (!active) return;
    const int g = blockIdx.x * 256 + threadIdx.x;     // [0, BIN_SZ*NCHUNK)
    const int c = g / BIN_SZ, e = g - c * BIN_SZ;
    const float* p = part + (size_t)c * KPC * BIN_SZ + e;
    float s = 0.0f;
    #pragma unroll 8
    for (int k = 0; k < KPC; ++k) s += p[(size_t)k * BIN_SZ];
    part2[g] = s;
}

__global__ __launch_bounds__(256) void finalize(const float* __restrict__ src,
                                                const int*   __restrict__ cnts,
                                                float* __restrict__ out,
                                                int n)
{
    const int idx = blockIdx.x * 256 + threadIdx.x;
    if (idx >= OUT_N) return;
    const int c   = idx & 63;
    const int s0  = (idx >> 6) % 94;
    const int b   = idx / (94 * 64);
    const int seg = s0 + 1;
    const int ch  = b * 64 + c;
    float s = 0.0f;
    for (int k = 0; k < n; ++k)
        s += src[(size_t)k * BIN_SZ + ch * PSEG + seg];
    const float den = fmaxf((float)cnts[seg], 1e-6f);
    out[idx] = s / den;
}

extern "C" void kernel_launch(void* const* d_in, const int* in_sizes, int n_in,
                              void* d_out, int out_size, void* d_ws, size_t ws_size,
                              hipStream_t stream)
{
    const float* feat  = (const float*)d_in[0];
    const int*   atlas = (const int*)d_in[1];
    float* out   = (float*)d_out;
    int*   cnts  = (int*)d_ws;
    float* part  = (float*)((char*)d_ws + PART_OFF);
    float* part2 = (float*)((char*)d_ws + PART2_OFF);
    const int use_atomic = (ws_size < WS_NEED) ? 1 : 0;

    const int nzero = (int)(PART_OFF / 4) + BIN_SZ;   // cnts + part[0] (atomic fallback)
    zero_ws<<<(nzero + 255) / 256, 256, 0, stream>>>((unsigned int*)d_ws);
    seg_count<<<256, 256, 0, stream>>>(atlas, cnts);
    seg_mfma<<<GRID, 256, 0, stream>>>(feat, atlas, part, use_atomic);
    reduce_stageA<<<(BIN_SZ * NCHUNK) / 256, 256, 0, stream>>>(part, part2, use_atomic ? 0 : 1);
    finalize<<<(OUT_N + 255) / 256, 256, 0, stream>>>(use_atomic ? part : part2, cnts, out,
                                                      use_atomic ? 1 : NCHUNK);
}

// Round 7
// 135.383 us; speedup vs baseline: 5.6932x; 1.0909x over previous
//
#include <hip/hip_runtime.h>

// ROI pooling 3D as one-hot MFMA GEMM (transposed): part[ch][seg] = sum_v feat[ch][v] * onehot[v][seg].
// Counts fused as row 128 via ones-vector GEMM (wave 0 only). No LDS, no atomics, deterministic tree.
constexpr int SEG_N   = 95;
constexpr int CROP_D  = 91, CROP_H = 109, CROP_W = 91;
constexpr int LINES   = CROP_D * CROP_H;              // 9919
constexpr int FEAT_W  = 96;
constexpr int FEAT_HW = 112 * 96;
constexpr int CSTRIDE = 96 * 112 * 96;                // per-(b,c) elements
constexpr int NTILE   = LINES * 3;                    // 29757 tiles of 32 voxels (exact)
constexpr int PSEG    = 96;                           // 95 segs + trash col 95
constexpr int ROWS    = 129;                          // 128 ch + counts row
constexpr int BIN_SZ  = ROWS * PSEG;                  // 12384 floats per partial
constexpr int GRID    = 1024;                         // 4 blocks/CU (VGPR-capped occupancy)
constexpr int NCHUNK  = 16;
constexpr int KPC     = GRID / NCHUNK;                // 64
constexpr int OUT_N   = 2 * 94 * 64;
constexpr size_t PART2_OFF = (size_t)GRID * BIN_SZ * sizeof(float);
constexpr size_t WS_NEED   = PART2_OFF + (size_t)NCHUNK * BIN_SZ * sizeof(float);

typedef __attribute__((ext_vector_type(8))) short bf16x8;
typedef __attribute__((ext_vector_type(4))) float f32x4;

__device__ inline unsigned int rne2(float a, float b) {   // 2x fp32 -> packed bf16 (RNE)
    unsigned int x = __float_as_uint(a), y = __float_as_uint(b);
    x = (x + 0x7FFFu + ((x >> 16) & 1u)) >> 16;
    y = (y + 0x7FFFu + ((y >> 16) & 1u)) & 0xFFFF0000u;
    return x | y;
}

__global__ __launch_bounds__(256) void zero_part(float* __restrict__ p)   // atomic-fallback only
{
    const int i = blockIdx.x * 256 + threadIdx.x;
    if (i < BIN_SZ) p[i] = 0.0f;
}

__global__ __launch_bounds__(256, 4) void seg_mfma(const float* __restrict__ feat,
                                                   const int*   __restrict__ atlas,
                                                   float* __restrict__ part,
                                                   int use_atomic)
{
    const int tid = threadIdx.x, wv = tid >> 6, lane = tid & 63;
    const int l15 = lane & 15, lq = lane >> 4;

    f32x4 acc[2][6];                                   // [ch-subtile][seg-tile]
    f32x4 accc[6];                                     // counts (live on wave 0 only)
    #pragma unroll
    for (int s = 0; s < 6; ++s) {
        acc[0][s] = (f32x4){0.f, 0.f, 0.f, 0.f};
        acc[1][s] = (f32x4){0.f, 0.f, 0.f, 0.f};
        accc[s]   = (f32x4){0.f, 0.f, 0.f, 0.f};
    }
    union { bf16x8 v; unsigned int u[4]; } ONES;
    ONES.u[0] = ONES.u[1] = ONES.u[2] = ONES.u[3] = 0x3F803F80u;

    for (int t = blockIdx.x; t < NTILE; t += GRID) {
        const int line  = t / 3;                       // tile = 32 voxels inside one 96-wide line
        const int w0    = (t - line * 3) * 32;
        const int d     = line / CROP_H, h = line - d * CROP_H;
        const int lbase = d * FEAT_HW + h * FEAT_W + w0;

        // atlas ids for this lane's k-quarter: k = lq*8 + j (w >= 91 -> trash seg 95)
        int id[8];
        const int wq = w0 + lq * 8, abase = line * CROP_W + w0 + lq * 8;
        #pragma unroll
        for (int j = 0; j < 8; ++j)
            id[j] = (wq + j < CROP_W) ? atlas[abase + j] : 95;

        // B one-hot fragments per seg-tile: col = l15 (seg), k = lq*8 + j
        bf16x8 bv[6];
        #pragma unroll
        for (int sb = 0; sb < 6; ++sb) {
            const int seg = sb * 16 + l15;
            union { bf16x8 v; unsigned int u[4]; } B;
            #pragma unroll
            for (int p = 0; p < 4; ++p) {
                const unsigned int lo = (id[2 * p]     == seg) ? 0x3F80u     : 0u;
                const unsigned int hi = (id[2 * p + 1] == seg) ? 0x3F800000u : 0u;
                B.u[p] = lo | hi;
            }
            bv[sb] = B.v;
        }

        // counts: D = ones * onehot (all D rows identical = per-seg tile count)
        if (wv == 0) {
            #pragma unroll
            for (int sb = 0; sb < 6; ++sb)
                accc[sb] = __builtin_amdgcn_mfma_f32_16x16x32_bf16(ONES.v, bv[sb], accc[sb], 0, 0, 0);
        }

        // A fragments: row = l15 -> ch, k = lq*8 + j. One full 128B line per (ch, tile).
        #pragma unroll
        for (int a = 0; a < 2; ++a) {
            const int ch = wv * 32 + a * 16 + l15;
            const float* fp = feat + (size_t)ch * CSTRIDE + lbase + lq * 8;
            const float4 v0 = *(const float4*)fp;
            const float4 v1 = *(const float4*)(fp + 4);
            union { bf16x8 v; unsigned int u[4]; } A;
            A.u[0] = rne2(v0.x, v0.y); A.u[1] = rne2(v0.z, v0.w);
            A.u[2] = rne2(v1.x, v1.y); A.u[3] = rne2(v1.z, v1.w);
            #pragma unroll
            for (int sb = 0; sb < 6; ++sb)
                acc[a][sb] = __builtin_amdgcn_mfma_f32_16x16x32_bf16(A.v, bv[sb], acc[a][sb], 0, 0, 0);
        }
    }

    // Epilogue: D row = lq*4 + r (ch within 16), col = l15 (seg). Waves own disjoint rows.
    float* p = part + (use_atomic ? 0 : (size_t)blockIdx.x * BIN_SZ);
    #pragma unroll
    for (int a = 0; a < 2; ++a)
        #pragma unroll
        for (int sb = 0; sb < 6; ++sb)
            #pragma unroll
            for (int r = 0; r < 4; ++r) {
                const int i = (wv * 32 + a * 16 + lq * 4 + r) * PSEG + sb * 16 + l15;
                if (use_atomic) unsafeAtomicAdd(&p[i], acc[a][sb][r]);
                else            p[i] = acc[a][sb][r];
            }
    if (wv == 0 && lq == 0) {                          // counts row (any D row; take reg 0)
        #pragma unroll
        for (int sb = 0; sb < 6; ++sb) {
            const int i = 128 * PSEG + sb * 16 + l15;
            if (use_atomic) unsafeAtomicAdd(&p[i], accc[sb][0]);
            else            p[i] = accc[sb][0];
        }
    }
}

// Stage A: sum GRID partials down to NCHUNK, coalesced across elem.
__global__ __launch_bounds__(256) void reduce_stageA(const float* __restrict__ part,
                                                     float* __restrict__ part2)
{
    const int g = blockIdx.x * 256 + threadIdx.x;     // [0, BIN_SZ*NCHUNK)
    const int c = g / BIN_SZ, e = g - c * BIN_SZ;
    const float* p = part + (size_t)c * KPC * BIN_SZ + e;
    float s = 0.0f;
    #pragma unroll 8
    for (int k = 0; k < KPC; ++k) s += p[(size_t)k * BIN_SZ];
    part2[g] = s;
}

__global__ __launch_bounds__(256) void finalize(const float* __restrict__ src,
                                                const int*   /*unused*/,
                                                float* __restrict__ out,
                                                int n)
{
    const int idx = blockIdx.x * 256 + threadIdx.x;
    if (idx >= OUT_N) return;
    const int c   = idx & 63;
    const int s0  = (idx >> 6) % 94;
    const int b   = idx / (94 * 64);
    const int seg = s0 + 1;
    const int ch  = b * 64 + c;
    float s = 0.0f, cnt = 0.0f;
    for (int k = 0; k < n; ++k) {
        s   += src[(size_t)k * BIN_SZ + ch * PSEG + seg];
        cnt += src[(size_t)k * BIN_SZ + 128 * PSEG + seg];
    }
    out[idx] = s / fmaxf(cnt, 1e-6f);
}

extern "C" void kernel_launch(void* const* d_in, const int* in_sizes, int n_in,
                              void* d_out, int out_size, void* d_ws, size_t ws_size,
                              hipStream_t stream)
{
    const float* feat  = (const float*)d_in[0];
    const int*   atlas = (const int*)d_in[1];
    float* out   = (float*)d_out;
    float* part  = (float*)d_ws;
    float* part2 = (float*)((char*)d_ws + PART2_OFF);
    const int use_atomic = (ws_size < WS_NEED) ? 1 : 0;

    if (use_atomic)
        zero_part<<<(BIN_SZ + 255) / 256, 256, 0, stream>>>(part);
    seg_mfma<<<GRID, 256, 0, stream>>>(feat, atlas, part, use_atomic);
    if (!use_atomic)
        reduce_stageA<<<(BIN_SZ * NCHUNK) / 256, 256, 0, stream>>>(part, part2);
    finalize<<<(OUT_N + 255) / 256, 256, 0, stream>>>(use_atomic ? part : part2, nullptr, out,
                                                      use_atomic ? 1 : NCHUNK);
}

// Round 8
// 133.743 us; speedup vs baseline: 5.7630x; 1.0123x over previous
//
#include <hip/hip_runtime.h>

// ROI pooling 3D as one-hot MFMA GEMM (transposed): part[ch][seg] = sum_v feat[ch][v] * onehot[v][seg].
// Counts fused as row 128 via ones-vector GEMM (wave 0 only). No LDS, no atomics, deterministic tree.
// R8: contiguous tile->block assignment for DRAM row-buffer locality (was grid-strided).
constexpr int SEG_N   = 95;
constexpr int CROP_D  = 91, CROP_H = 109, CROP_W = 91;
constexpr int LINES   = CROP_D * CROP_H;              // 9919
constexpr int FEAT_W  = 96;
constexpr int FEAT_HW = 112 * 96;
constexpr int CSTRIDE = 96 * 112 * 96;                // per-(b,c) elements
constexpr int NTILE   = LINES * 3;                    // 29757 tiles of 32 voxels (exact)
constexpr int PSEG    = 96;                           // 95 segs + trash col 95
constexpr int ROWS    = 129;                          // 128 ch + counts row
constexpr int BIN_SZ  = ROWS * PSEG;                  // 12384 floats per partial
constexpr int GRID    = 1024;                         // 4 blocks/CU
constexpr int NCHUNK  = 16;
constexpr int KPC     = GRID / NCHUNK;                // 64
constexpr int OUT_N   = 2 * 94 * 64;
constexpr size_t PART2_OFF = (size_t)GRID * BIN_SZ * sizeof(float);
constexpr size_t WS_NEED   = PART2_OFF + (size_t)NCHUNK * BIN_SZ * sizeof(float);

typedef __attribute__((ext_vector_type(8))) short bf16x8;
typedef __attribute__((ext_vector_type(4))) float f32x4;

__device__ inline unsigned int rne2(float a, float b) {   // 2x fp32 -> packed bf16 (RNE)
    unsigned int x = __float_as_uint(a), y = __float_as_uint(b);
    x = (x + 0x7FFFu + ((x >> 16) & 1u)) >> 16;
    y = (y + 0x7FFFu + ((y >> 16) & 1u)) & 0xFFFF0000u;
    return x | y;
}

__global__ __launch_bounds__(256) void zero_part(float* __restrict__ p)   // atomic-fallback only
{
    const int i = blockIdx.x * 256 + threadIdx.x;
    if (i < BIN_SZ) p[i] = 0.0f;
}

__global__ __launch_bounds__(256, 4) void seg_mfma(const float* __restrict__ feat,
                                                   const int*   __restrict__ atlas,
                                                   float* __restrict__ part,
                                                   int use_atomic)
{
    const int tid = threadIdx.x, wv = tid >> 6, lane = tid & 63;
    const int l15 = lane & 15, lq = lane >> 4;

    f32x4 acc[2][6];                                   // [ch-subtile][seg-tile]
    f32x4 accc[6];                                     // counts (live on wave 0 only)
    #pragma unroll
    for (int s = 0; s < 6; ++s) {
        acc[0][s] = (f32x4){0.f, 0.f, 0.f, 0.f};
        acc[1][s] = (f32x4){0.f, 0.f, 0.f, 0.f};
        accc[s]   = (f32x4){0.f, 0.f, 0.f, 0.f};
    }
    union { bf16x8 v; unsigned int u[4]; } ONES;
    ONES.u[0] = ONES.u[1] = ONES.u[2] = ONES.u[3] = 0x3F803F80u;

    // Contiguous balanced chunk per block: DRAM streams advance sequentially.
    const int base = NTILE / GRID, rem = NTILE % GRID;            // 29, 61
    const int bx   = blockIdx.x;
    const int t0   = bx * base + (bx < rem ? bx : rem);
    const int te   = t0 + base + (bx < rem ? 1 : 0);

    for (int t = t0; t < te; ++t) {
        const int line  = t / 3;                       // tile = 32 voxels inside one 96-wide line
        const int w0    = (t - line * 3) * 32;
        const int d     = line / CROP_H, h = line - d * CROP_H;
        const int lbase = d * FEAT_HW + h * FEAT_W + w0;

        // atlas ids for this lane's k-quarter: k = lq*8 + j (w >= 91 -> trash seg 95)
        int id[8];
        const int wq = w0 + lq * 8, abase = line * CROP_W + w0 + lq * 8;
        #pragma unroll
        for (int j = 0; j < 8; ++j)
            id[j] = (wq + j < CROP_W) ? atlas[abase + j] : 95;

        // B one-hot fragments per seg-tile: col = l15 (seg), k = lq*8 + j
        bf16x8 bv[6];
        #pragma unroll
        for (int sb = 0; sb < 6; ++sb) {
            const int seg = sb * 16 + l15;
            union { bf16x8 v; unsigned int u[4]; } B;
            #pragma unroll
            for (int p = 0; p < 4; ++p) {
                const unsigned int lo = (id[2 * p]     == seg) ? 0x3F80u     : 0u;
                const unsigned int hi = (id[2 * p + 1] == seg) ? 0x3F800000u : 0u;
                B.u[p] = lo | hi;
            }
            bv[sb] = B.v;
        }

        // counts: D = ones * onehot (all D rows identical = per-seg tile count)
        if (wv == 0) {
            #pragma unroll
            for (int sb = 0; sb < 6; ++sb)
                accc[sb] = __builtin_amdgcn_mfma_f32_16x16x32_bf16(ONES.v, bv[sb], accc[sb], 0, 0, 0);
        }

        // A fragments: row = l15 -> ch, k = lq*8 + j. One full 128B line per (ch, tile).
        #pragma unroll
        for (int a = 0; a < 2; ++a) {
            const int ch = wv * 32 + a * 16 + l15;
            const float* fp = feat + (size_t)ch * CSTRIDE + lbase + lq * 8;
            const float4 v0 = *(const float4*)fp;
            const float4 v1 = *(const float4*)(fp + 4);
            union { bf16x8 v; unsigned int u[4]; } A;
            A.u[0] = rne2(v0.x, v0.y); A.u[1] = rne2(v0.z, v0.w);
            A.u[2] = rne2(v1.x, v1.y); A.u[3] = rne2(v1.z, v1.w);
            #pragma unroll
            for (int sb = 0; sb < 6; ++sb)
                acc[a][sb] = __builtin_amdgcn_mfma_f32_16x16x32_bf16(A.v, bv[sb], acc[a][sb], 0, 0, 0);
        }
    }

    // Epilogue: D row = lq*4 + r (ch within 16), col = l15 (seg). Waves own disjoint rows.
    float* p = part + (use_atomic ? 0 : (size_t)blockIdx.x * BIN_SZ);
    #pragma unroll
    for (int a = 0; a < 2; ++a)
        #pragma unroll
        for (int sb = 0; sb < 6; ++sb)
            #pragma unroll
            for (int r = 0; r < 4; ++r) {
                const int i = (wv * 32 + a * 16 + lq * 4 + r) * PSEG + sb * 16 + l15;
                if (use_atomic) unsafeAtomicAdd(&p[i], acc[a][sb][r]);
                else            p[i] = acc[a][sb][r];
            }
    if (wv == 0 && lq == 0) {                          // counts row (any D row; take reg 0)
        #pragma unroll
        for (int sb = 0; sb < 6; ++sb) {
            const int i = 128 * PSEG + sb * 16 + l15;
            if (use_atomic) unsafeAtomicAdd(&p[i], accc[sb][0]);
            else            p[i] = accc[sb][0];
        }
    }
}

// Stage A: sum GRID partials down to NCHUNK, coalesced across elem.
__global__ __launch_bounds__(256) void reduce_stageA(const float* __restrict__ part,
                                                     float* __restrict__ part2)
{
    const int g = blockIdx.x * 256 + threadIdx.x;     // [0, BIN_SZ*NCHUNK)
    const int c = g / BIN_SZ, e = g - c * BIN_SZ;
    const float* p = part + (size_t)c * KPC * BIN_SZ + e;
    float s = 0.0f;
    #pragma unroll 8
    for (int k = 0; k < KPC; ++k) s += p[(size_t)k * BIN_SZ];
    part2[g] = s;
}

__global__ __launch_bounds__(256) void finalize(const float* __restrict__ src,
                                                float* __restrict__ out,
                                                int n)
{
    const int idx = blockIdx.x * 256 + threadIdx.x;
    if (idx >= OUT_N) return;
    const int c   = idx & 63;
    const int s0  = (idx >> 6) % 94;
    const int b   = idx / (94 * 64);
    const int seg = s0 + 1;
    const int ch  = b * 64 + c;
    float s = 0.0f, cnt = 0.0f;
    for (int k = 0; k < n; ++k) {
        s   += src[(size_t)k * BIN_SZ + ch * PSEG + seg];
        cnt += src[(size_t)k * BIN_SZ + 128 * PSEG + seg];
    }
    out[idx] = s / fmaxf(cnt, 1e-6f);
}

extern "C" void kernel_launch(void* const* d_in, const int* in_sizes, int n_in,
                              void* d_out, int out_size, void* d_ws, size_t ws_size,
                              hipStream_t stream)
{
    const float* feat  = (const float*)d_in[0];
    const int*   atlas = (const int*)d_in[1];
    float* out   = (float*)d_out;
    float* part  = (float*)d_ws;
    float* part2 = (float*)((char*)d_ws + PART2_OFF);
    const int use_atomic = (ws_size < WS_NEED) ? 1 : 0;

    if (use_atomic)
        zero_part<<<(BIN_SZ + 255) / 256, 256, 0, stream>>>(part);
    seg_mfma<<<GRID, 256, 0, stream>>>(feat, atlas, part, use_atomic);
    if (!use_atomic)
        reduce_stageA<<<(BIN_SZ * NCHUNK) / 256, 256, 0, stream>>>(part, part2);
    finalize<<<(OUT_N + 255) / 256, 256, 0, stream>>>(use_atomic ? part : part2, out,
                                                      use_atomic ? 1 : NCHUNK);
}